// Round 1
// baseline (109.999 us; speedup 1.0000x reference)
//
#include <hip/hip_runtime.h>
#include <hip/hip_bf16.h>
#include <hip/hip_fp8.h>

// SimCLR NT-Xent loss on MI355X.
// loss = -(1/2B) sum_t [ 10*G[t,j0(t)] - (10 + log sum_{j!=t} exp(10*G[t,j]-10)) ]
// where G = M M^T, M = l2norm rows of [z_i; z_j], j0 = (t%B==0) ? 1 : 0.
// Round 6: double-buffered LDS prefetch in the Gram K-loop.
//   old: barrier -> stage -> barrier(vmcnt0 drain) -> compute   (latency exposed, 2 bar/chunk)
//   new: barrier -> issue stage(t+1) -> compute(t)              (latency hidden,  1 bar/chunk)
// The lone __syncthreads at loop top drains only loads issued one full
// compute-phase earlier (residual ~0). LDS 64 KB -> 2 blocks/CU; prefetch
// replaces the lost inter-block overlap. Epilogue exp folded to fma+v_exp.

#define BB 4096      // batch B
#define DD 512       // feature dim (bytes per row in fp8)
#define NN 8192      // 2B rows of G
#define TILE 128     // block tile (rows x cols)
#define KB 128       // K bytes (=elements) staged per LDS chunk
#define NBLK 2080    // 64*65/2 upper-triangle block tiles

typedef __attribute__((ext_vector_type(4))) float f32x4;

#define AS1 __attribute__((address_space(1)))
#define AS3 __attribute__((address_space(3)))
static __device__ __forceinline__ void gload_lds16(const void* g, void* l) {
    __builtin_amdgcn_global_load_lds((const AS1 void*)g, (AS3 void*)l, 16, 0, 0);
}

// ---------------- kernel 1: L2-normalize rows, cast to fp8; zero rowsum ----
// One wave per row: 64 lanes x 8 f32, shuffle reduce, no LDS/barrier.
__global__ __launch_bounds__(256)
void normalize_kernel(const float* __restrict__ zi, const float* __restrict__ zj,
                      unsigned char* __restrict__ M, float* __restrict__ rowsum) {
    const int wave = threadIdx.x >> 6;
    const int lane = threadIdx.x & 63;
    const int row  = blockIdx.x * 4 + wave;      // 2048 blocks * 4 rows
    if (threadIdx.x < 4) rowsum[blockIdx.x * 4 + threadIdx.x] = 0.f;
    const float* src = (row < BB) ? (zi + (size_t)row * DD)
                                  : (zj + (size_t)(row - BB) * DD);
    float4 v0 = ((const float4*)src)[lane * 2 + 0];
    float4 v1 = ((const float4*)src)[lane * 2 + 1];
    float ss = v0.x*v0.x + v0.y*v0.y + v0.z*v0.z + v0.w*v0.w
             + v1.x*v1.x + v1.y*v1.y + v1.z*v1.z + v1.w*v1.w;
    #pragma unroll
    for (int off = 1; off <= 32; off <<= 1) ss += __shfl_xor(ss, off);
    const float inv = rsqrtf(ss);
    const float vals[8] = {v0.x*inv, v0.y*inv, v0.z*inv, v0.w*inv,
                           v1.x*inv, v1.y*inv, v1.z*inv, v1.w*inv};
    union { long u; unsigned char b[8]; } pk;
    #pragma unroll
    for (int j = 0; j < 8; ++j)
        pk.b[j] = __hip_cvt_float_to_fp8(vals[j], __HIP_SATFINITE, __HIP_E4M3);
    ((long*)(M + (size_t)row * DD))[lane] = pk.u;
}

// ---------------- kernel 2: Gram tile + exp row/col sums -------------------
// 2080 blocks, one upper-triangle 128x128 tile each (by >= bx).
// Wave w: rows wr=(w>>1)*64, cols wc=(w&1)*64 within the tile.
// LDS: double-buffered; each buffer row-major 128 rows x 128 B, XOR-swizzled
// 16B granules: granule q holds (row=q>>3, g=(q&7)^((q>>3)&7)); gather side
// inverts the swizzle so global_load_lds's lane-linear dest is satisfied.
__global__ __launch_bounds__(256, 2)
void gram_lse_kernel(const unsigned char* __restrict__ Mg,
                     float* __restrict__ rowsum, float* __restrict__ targets) {
    __shared__ __align__(16) char As[2][TILE * KB];   // 2 x 16 KB
    __shared__ __align__(16) char Bs[2][TILE * KB];   // 2 x 16 KB

    // XCD-banded order: dispatch d -> band d%8 (one XCD), 260 tiles per band.
    const int d = blockIdx.x;
    const int p = (d & 7) * 260 + (d >> 3);
    // triangular decode: p -> (bx, by) with by >= bx
    int by = (int)((sqrtf(8.0f * (float)p + 1.0f) - 1.0f) * 0.5f);
    while ((by + 1) * (by + 2) / 2 <= p) ++by;
    while (by * (by + 1) / 2 > p) --by;
    const int bx = p - by * (by + 1) / 2;

    const int rowBase = bx * TILE;
    const int colBase = by * TILE;
    const bool diag = (bx == by);
    const int tid  = threadIdx.x;
    const int wave = tid >> 6;
    const int lane = tid & 63;
    const int wr = (wave >> 1) * 64;
    const int wc = (wave & 1) * 64;
    const int l15 = lane & 15;
    const int l4  = lane >> 4;          // quad 0..3

    // staging gather pattern (constant per thread across issues & k0):
    const int sg  = (tid & 7) ^ ((tid >> 3) & 7);   // source granule within row
    const int sr0 = tid >> 3;                        // source row base (+32/issue)
    const unsigned char* gA0 = Mg + (size_t)(rowBase + sr0) * DD + sg * 16;
    const unsigned char* gB0 = Mg + (size_t)(colBase + sr0) * DD + sg * 16;

    // fragment read pattern: row r fragment for k-step ks at
    //   r*128 + (((ks*2 + (l4>>1)) ^ (r&7))*16) + (l4&1)*8   [8B aligned]
    // r&7 == l15&7 for all mi/ni since tile row strides are multiples of 16.
    const int r7 = l15 & 7;
    const int qh = l4 >> 1, ql = l4 & 1;
    const int aoff0 = (wr + l15) * KB + ql * 8;
    const int boff0 = (wc + l15) * KB + ql * 8;

    f32x4 acc[4][4] = {};

    // ---- prologue: stage chunk 0 into buffer 0 ----
    {
        char* lA = As[0] + tid * 16;
        #pragma unroll
        for (int i = 0; i < 4; ++i)
            gload_lds16(gA0 + (size_t)i * 32 * DD, lA + i * 4096);
        if (!diag) {
            char* lB = Bs[0] + tid * 16;
            #pragma unroll
            for (int i = 0; i < 4; ++i)
                gload_lds16(gB0 + (size_t)i * 32 * DD, lB + i * 4096);
        }
    }

    // ---- main loop: one barrier per chunk; stage(t+1) overlaps compute(t) ----
    #pragma unroll
    for (int t = 0; t < DD / KB; ++t) {
        // Drains vmcnt(0): chunk t (issued one full compute phase ago) has
        // landed in buffer t&1; buffer (t+1)&1 is no longer being read.
        __syncthreads();
        if (t < DD / KB - 1) {
            const int k0 = (t + 1) * KB;
            char* lA = As[(t + 1) & 1] + tid * 16;
            #pragma unroll
            for (int i = 0; i < 4; ++i)
                gload_lds16(gA0 + k0 + (size_t)i * 32 * DD, lA + i * 4096);
            if (!diag) {
                char* lB = Bs[(t + 1) & 1] + tid * 16;
                #pragma unroll
                for (int i = 0; i < 4; ++i)
                    gload_lds16(gB0 + k0 + (size_t)i * 32 * DD, lB + i * 4096);
            }
        }
        const char* Asrc = As[t & 1];
        const char* Bsrc = diag ? Asrc : Bs[t & 1];
        #pragma unroll
        for (int ks = 0; ks < 4; ++ks) {
            const int so = ((((ks << 1) | qh) ^ r7) << 4);
            long a[4], b[4];
            #pragma unroll
            for (int mi = 0; mi < 4; ++mi)
                a[mi] = *(const long*)(Asrc + aoff0 + mi * 2048 + so);
            #pragma unroll
            for (int ni = 0; ni < 4; ++ni)
                b[ni] = *(const long*)(Bsrc + boff0 + ni * 2048 + so);
            #pragma unroll
            for (int mi = 0; mi < 4; ++mi)
                #pragma unroll
                for (int ni = 0; ni < 4; ++ni)
                    acc[mi][ni] = __builtin_amdgcn_mfma_f32_16x16x32_fp8_fp8(
                        a[mi], b[ni], acc[mi][ni], 0, 0, 0);
        }
    }

    // ---- epilogue ----
    // C/D layout: col = lane&15, row = (lane>>4)*4 + reg  (dtype-independent)
    // e = exp(10*G - 10) = exp2(G*C - C), C = 10*log2(e): one fma + one v_exp.
    const float C10 = 14.42695040888963f;
    float cs[4] = {0.f, 0.f, 0.f, 0.f};   // column partials (off-diag tiles)
    #pragma unroll
    for (int mi = 0; mi < 4; ++mi) {
        float rs[4] = {0.f, 0.f, 0.f, 0.f};
        #pragma unroll
        for (int ni = 0; ni < 4; ++ni) {
            const int gcol = colBase + wc + ni * 16 + l15;
            #pragma unroll
            for (int r = 0; r < 4; ++r) {
                const int grow = rowBase + wr + mi * 16 + l4 * 4 + r;
                float e = __builtin_amdgcn_exp2f(fmaf(acc[mi][ni][r], C10, -C10));
                if (grow == gcol) e = 0.f;     // exclude diagonal exactly
                rs[r] += e;
                cs[ni] += e;
                // targets: rows 0/1 of G give 10*G[t, j0] transposed.
                // Only bx==0 blocks write; disjoint col ranges -> plain store.
                if (rowBase == 0 && grow < 2) {
                    const int j0 = ((gcol & (BB - 1)) == 0) ? 1 : 0;
                    if (grow == j0) targets[gcol] = 10.f * acc[mi][ni][r];
                }
            }
        }
        #pragma unroll
        for (int m = 1; m <= 8; m <<= 1)
            #pragma unroll
            for (int r = 0; r < 4; ++r)
                rs[r] += __shfl_xor(rs[r], m);
        if (l15 == 0) {
            #pragma unroll
            for (int r = 0; r < 4; ++r)
                atomicAdd(&rowsum[rowBase + wr + mi * 16 + l4 * 4 + r], rs[r]);
        }
    }
    if (!diag) {
        #pragma unroll
        for (int ni = 0; ni < 4; ++ni) {
            cs[ni] += __shfl_xor(cs[ni], 16);
            cs[ni] += __shfl_xor(cs[ni], 32);
        }
        if (l4 == 0) {
            #pragma unroll
            for (int ni = 0; ni < 4; ++ni)
                atomicAdd(&rowsum[colBase + wc + ni * 16 + l15], cs[ni]);
        }
    }
}

// ---------------- kernel 3: final scalar reduction -------------------------
__global__ __launch_bounds__(1024)
void finalize_kernel(const float* __restrict__ rowsum,
                     const float* __restrict__ targets, float* __restrict__ out) {
    const int tid = threadIdx.x;
    float s = 0.f;
    #pragma unroll
    for (int t = tid; t < NN; t += 1024)
        s += targets[t] - 10.f - __logf(rowsum[t]);
    #pragma unroll
    for (int off = 1; off <= 32; off <<= 1) s += __shfl_xor(s, off);
    __shared__ float red[16];
    if ((tid & 63) == 0) red[tid >> 6] = s;
    __syncthreads();
    if (tid == 0) {
        float t = 0.f;
        #pragma unroll
        for (int i = 0; i < 16; ++i) t += red[i];
        out[0] = -t / (float)NN;
    }
}

extern "C" void kernel_launch(void* const* d_in, const int* in_sizes, int n_in,
                              void* d_out, int out_size, void* d_ws, size_t ws_size,
                              hipStream_t stream) {
    const float* zi = (const float*)d_in[0];
    const float* zj = (const float*)d_in[1];

    unsigned char* M = (unsigned char*)d_ws;                         // 4 MB fp8
    float* rowsum  = (float*)((char*)d_ws + (size_t)NN * DD);        // 32 KB
    float* targets = rowsum + NN;                                    // 32 KB
    float* out = (float*)d_out;

    normalize_kernel<<<NN / 4, 256, 0, stream>>>(zi, zj, M, rowsum);
    gram_lse_kernel<<<NBLK, 256, 0, stream>>>(M, rowsum, targets);
    finalize_kernel<<<1, 1024, 0, stream>>>(rowsum, targets, out);
}

// Round 2
// 102.898 us; speedup vs baseline: 1.0690x; 1.0690x over previous
//
#include <hip/hip_runtime.h>
#include <hip/hip_bf16.h>
#include <hip/hip_fp8.h>

// SimCLR NT-Xent loss on MI355X.
// loss = -(1/2B) sum_t [ 10*G[t,j0(t)] - (10 + log sum_{j!=t} exp(10*G[t,j]-10)) ]
// where G = M M^T, M = l2norm rows of [z_i; z_j], j0 = (t%B==0) ? 1 : 0.
// Round 7: KB=64 double-buffer. Round-6 lesson: 64 KB LDS -> 2 blocks/CU
// killed inter-block overlap (occupancy 17%). Halve the chunk so the
// double-buffered pipeline fits in 32 KB -> 4 blocks/CU, keeping the
// 1-barrier stage(t+1)-overlaps-compute(t) schedule. Swizzle re-derived
// for 64B rows: stored granule = g ^ ((row>>1)&3) puts the wave's 64
// b64-lanes at exactly 4 per 8B-slot = LDS service minimum.

#define BB 4096      // batch B
#define DD 512       // feature dim (bytes per row in fp8)
#define NN 8192      // 2B rows of G
#define TILE 128     // block tile (rows x cols)
#define KB 64        // K bytes (=elements) staged per LDS chunk
#define NBLK 2080    // 64*65/2 upper-triangle block tiles

typedef __attribute__((ext_vector_type(4))) float f32x4;

#define AS1 __attribute__((address_space(1)))
#define AS3 __attribute__((address_space(3)))
static __device__ __forceinline__ void gload_lds16(const void* g, void* l) {
    __builtin_amdgcn_global_load_lds((const AS1 void*)g, (AS3 void*)l, 16, 0, 0);
}

// ---------------- kernel 1: L2-normalize rows, cast to fp8; zero rowsum ----
// One wave per row: 64 lanes x 8 f32, shuffle reduce, no LDS/barrier.
__global__ __launch_bounds__(256)
void normalize_kernel(const float* __restrict__ zi, const float* __restrict__ zj,
                      unsigned char* __restrict__ M, float* __restrict__ rowsum) {
    const int wave = threadIdx.x >> 6;
    const int lane = threadIdx.x & 63;
    const int row  = blockIdx.x * 4 + wave;      // 2048 blocks * 4 rows
    if (threadIdx.x < 4) rowsum[blockIdx.x * 4 + threadIdx.x] = 0.f;
    const float* src = (row < BB) ? (zi + (size_t)row * DD)
                                  : (zj + (size_t)(row - BB) * DD);
    float4 v0 = ((const float4*)src)[lane * 2 + 0];
    float4 v1 = ((const float4*)src)[lane * 2 + 1];
    float ss = v0.x*v0.x + v0.y*v0.y + v0.z*v0.z + v0.w*v0.w
             + v1.x*v1.x + v1.y*v1.y + v1.z*v1.z + v1.w*v1.w;
    #pragma unroll
    for (int off = 1; off <= 32; off <<= 1) ss += __shfl_xor(ss, off);
    const float inv = rsqrtf(ss);
    const float vals[8] = {v0.x*inv, v0.y*inv, v0.z*inv, v0.w*inv,
                           v1.x*inv, v1.y*inv, v1.z*inv, v1.w*inv};
    union { long u; unsigned char b[8]; } pk;
    #pragma unroll
    for (int j = 0; j < 8; ++j)
        pk.b[j] = __hip_cvt_float_to_fp8(vals[j], __HIP_SATFINITE, __HIP_E4M3);
    ((long*)(M + (size_t)row * DD))[lane] = pk.u;
}

// ---------------- kernel 2: Gram tile + exp row/col sums -------------------
// 2080 blocks, one upper-triangle 128x128 tile each (by >= bx).
// Wave w: rows wr=(w>>1)*64, cols wc=(w&1)*64 within the tile.
// LDS: double-buffered; each buffer row-major 128 rows x 64 B, XOR-swizzled
// 16B granules: row r stores source granule sg at position sg ^ ((r>>1)&3).
// Gather side inverts the swizzle so global_load_lds's lane-linear dest
// constraint is satisfied (source addr carries the permutation).
__global__ __launch_bounds__(256, 4)
void gram_lse_kernel(const unsigned char* __restrict__ Mg,
                     float* __restrict__ rowsum, float* __restrict__ targets) {
    __shared__ __align__(16) char As[2][TILE * KB];   // 2 x 8 KB
    __shared__ __align__(16) char Bs[2][TILE * KB];   // 2 x 8 KB

    // XCD-banded order: dispatch d -> band d%8 (one XCD), 260 tiles per band.
    const int d = blockIdx.x;
    const int p = (d & 7) * 260 + (d >> 3);
    // triangular decode: p -> (bx, by) with by >= bx
    int by = (int)((sqrtf(8.0f * (float)p + 1.0f) - 1.0f) * 0.5f);
    while ((by + 1) * (by + 2) / 2 <= p) ++by;
    while (by * (by + 1) / 2 > p) --by;
    const int bx = p - by * (by + 1) / 2;

    const int rowBase = bx * TILE;
    const int colBase = by * TILE;
    const bool diag = (bx == by);
    const int tid  = threadIdx.x;
    const int wave = tid >> 6;
    const int lane = tid & 63;
    const int wr = (wave >> 1) * 64;
    const int wc = (wave & 1) * 64;
    const int l15 = lane & 15;
    const int l4  = lane >> 4;          // quad 0..3

    // staging gather pattern (constant per thread across issues & chunks):
    //   dest granule q = issue*256 + tid -> row = issue*64 + (tid>>2),
    //   stored pos s = tid&3, source granule sg = s ^ swz(row),
    //   swz(row) = (row>>1)&3 = (tid>>3)&3  (issue*64 drops out mod 4).
    const int sg  = (tid & 3) ^ ((tid >> 3) & 3);   // source granule within row
    const int sr0 = tid >> 2;                        // source row base (+64/issue)
    const unsigned char* gA0 = Mg + (size_t)(rowBase + sr0) * DD + sg * 16;
    const unsigned char* gB0 = Mg + (size_t)(colBase + sr0) * DD + sg * 16;

    // fragment read pattern: row r = wr/wc + l15 + mi*16, source granule
    // g = ks*2 + (l4>>1) lives at position g ^ ((r>>1)&3); (r>>1)&3 ==
    // (l15>>1)&3 since wr/wc + mi*16 are multiples of 16.
    const int r2 = (l15 >> 1) & 3;
    const int qh = l4 >> 1, ql = l4 & 1;
    const int aoff0 = (wr + l15) * KB + ql * 8;
    const int boff0 = (wc + l15) * KB + ql * 8;

    f32x4 acc[4][4] = {};

    // ---- prologue: stage chunk 0 into buffer 0 ----
    {
        char* lA = As[0] + tid * 16;
        #pragma unroll
        for (int i = 0; i < 2; ++i)
            gload_lds16(gA0 + (size_t)i * 64 * DD, lA + i * 4096);
        if (!diag) {
            char* lB = Bs[0] + tid * 16;
            #pragma unroll
            for (int i = 0; i < 2; ++i)
                gload_lds16(gB0 + (size_t)i * 64 * DD, lB + i * 4096);
        }
    }

    // ---- main loop: one barrier per chunk; stage(t+1) overlaps compute(t) ----
    #pragma unroll
    for (int t = 0; t < DD / KB; ++t) {
        // Drains vmcnt(0): chunk t (issued one full compute phase ago) has
        // landed in buffer t&1; buffer (t+1)&1 is no longer being read.
        __syncthreads();
        if (t < DD / KB - 1) {
            const int k0 = (t + 1) * KB;
            char* lA = As[(t + 1) & 1] + tid * 16;
            #pragma unroll
            for (int i = 0; i < 2; ++i)
                gload_lds16(gA0 + k0 + (size_t)i * 64 * DD, lA + i * 4096);
            if (!diag) {
                char* lB = Bs[(t + 1) & 1] + tid * 16;
                #pragma unroll
                for (int i = 0; i < 2; ++i)
                    gload_lds16(gB0 + k0 + (size_t)i * 64 * DD, lB + i * 4096);
            }
        }
        const char* Asrc = As[t & 1];
        const char* Bsrc = diag ? Asrc : Bs[t & 1];
        #pragma unroll
        for (int ks = 0; ks < 2; ++ks) {
            const int so = ((((ks << 1) | qh) ^ r2) << 4);
            long a[4], b[4];
            #pragma unroll
            for (int mi = 0; mi < 4; ++mi)
                a[mi] = *(const long*)(Asrc + aoff0 + mi * 1024 + so);
            #pragma unroll
            for (int ni = 0; ni < 4; ++ni)
                b[ni] = *(const long*)(Bsrc + boff0 + ni * 1024 + so);
            #pragma unroll
            for (int mi = 0; mi < 4; ++mi)
                #pragma unroll
                for (int ni = 0; ni < 4; ++ni)
                    acc[mi][ni] = __builtin_amdgcn_mfma_f32_16x16x32_fp8_fp8(
                        a[mi], b[ni], acc[mi][ni], 0, 0, 0);
        }
    }

    // ---- epilogue ----
    // C/D layout: col = lane&15, row = (lane>>4)*4 + reg  (dtype-independent)
    // e = exp(10*G - 10) = exp2(G*C - C), C = 10*log2(e): one fma + one v_exp.
    const float C10 = 14.42695040888963f;
    float cs[4] = {0.f, 0.f, 0.f, 0.f};   // column partials (off-diag tiles)
    #pragma unroll
    for (int mi = 0; mi < 4; ++mi) {
        float rs[4] = {0.f, 0.f, 0.f, 0.f};
        #pragma unroll
        for (int ni = 0; ni < 4; ++ni) {
            const int gcol = colBase + wc + ni * 16 + l15;
            #pragma unroll
            for (int r = 0; r < 4; ++r) {
                const int grow = rowBase + wr + mi * 16 + l4 * 4 + r;
                float e = __builtin_amdgcn_exp2f(fmaf(acc[mi][ni][r], C10, -C10));
                if (grow == gcol) e = 0.f;     // exclude diagonal exactly
                rs[r] += e;
                cs[ni] += e;
                // targets: rows 0/1 of G give 10*G[t, j0] transposed.
                // Only bx==0 blocks write; disjoint col ranges -> plain store.
                if (rowBase == 0 && grow < 2) {
                    const int j0 = ((gcol & (BB - 1)) == 0) ? 1 : 0;
                    if (grow == j0) targets[gcol] = 10.f * acc[mi][ni][r];
                }
            }
        }
        #pragma unroll
        for (int m = 1; m <= 8; m <<= 1)
            #pragma unroll
            for (int r = 0; r < 4; ++r)
                rs[r] += __shfl_xor(rs[r], m);
        if (l15 == 0) {
            #pragma unroll
            for (int r = 0; r < 4; ++r)
                atomicAdd(&rowsum[rowBase + wr + mi * 16 + l4 * 4 + r], rs[r]);
        }
    }
    if (!diag) {
        #pragma unroll
        for (int ni = 0; ni < 4; ++ni) {
            cs[ni] += __shfl_xor(cs[ni], 16);
            cs[ni] += __shfl_xor(cs[ni], 32);
        }
        if (l4 == 0) {
            #pragma unroll
            for (int ni = 0; ni < 4; ++ni)
                atomicAdd(&rowsum[colBase + wc + ni * 16 + l15], cs[ni]);
        }
    }
}

// ---------------- kernel 3: final scalar reduction -------------------------
__global__ __launch_bounds__(1024)
void finalize_kernel(const float* __restrict__ rowsum,
                     const float* __restrict__ targets, float* __restrict__ out) {
    const int tid = threadIdx.x;
    float s = 0.f;
    #pragma unroll
    for (int t = tid; t < NN; t += 1024)
        s += targets[t] - 10.f - __logf(rowsum[t]);
    #pragma unroll
    for (int off = 1; off <= 32; off <<= 1) s += __shfl_xor(s, off);
    __shared__ float red[16];
    if ((tid & 63) == 0) red[tid >> 6] = s;
    __syncthreads();
    if (tid == 0) {
        float t = 0.f;
        #pragma unroll
        for (int i = 0; i < 16; ++i) t += red[i];
        out[0] = -t / (float)NN;
    }
}

extern "C" void kernel_launch(void* const* d_in, const int* in_sizes, int n_in,
                              void* d_out, int out_size, void* d_ws, size_t ws_size,
                              hipStream_t stream) {
    const float* zi = (const float*)d_in[0];
    const float* zj = (const float*)d_in[1];

    unsigned char* M = (unsigned char*)d_ws;                         // 4 MB fp8
    float* rowsum  = (float*)((char*)d_ws + (size_t)NN * DD);        // 32 KB
    float* targets = rowsum + NN;                                    // 32 KB
    float* out = (float*)d_out;

    normalize_kernel<<<NN / 4, 256, 0, stream>>>(zi, zj, M, rowsum);
    gram_lse_kernel<<<NBLK, 256, 0, stream>>>(M, rowsum, targets);
    finalize_kernel<<<1, 1024, 0, stream>>>(rowsum, targets, out);
}